// Round 5
// baseline (4110.903 us; speedup 1.0000x reference)
//
#include <hip/hip_runtime.h>
#include <math.h>

#define Bq 64
#define Tq 512
#define Hq 1024
#define G4 4096
#define NBLK 256
#define NTHR 512

typedef __attribute__((ext_vector_type(8))) short short8;    // 8 bf16
typedef __attribute__((ext_vector_type(4))) float float4v;   // MFMA acc
typedef __attribute__((ext_vector_type(4))) unsigned uint4v; // dwordx4 payload

static __device__ __forceinline__ short f2bf(float f) {
    union { float f; unsigned u; } c; c.f = f;
    unsigned r = (c.u + 0x7fffu + ((c.u >> 16) & 1u)) >> 16;  // RNE
    return (short)r;
}

// agent-scope relaxed atomics (cache-bypass to coherence point; no fences)
static __device__ __forceinline__ void astore_u(unsigned* p, unsigned v) {
    __hip_atomic_store(p, v, __ATOMIC_RELAXED, __HIP_MEMORY_SCOPE_AGENT);
}
static __device__ __forceinline__ unsigned aload_u(const unsigned* p) {
    return __hip_atomic_load(p, __ATOMIC_RELAXED, __HIP_MEMORY_SCOPE_AGENT);
}

static __device__ __forceinline__ float fsig(float v) {
    return 1.f / (1.f + __expf(-v));
}
static __device__ __forceinline__ float ftanh(float v) {
    float cl = fminf(fmaxf(v, -15.f), 15.f);   // keep __expf finite
    float e  = __expf(-2.f * cl);
    return (1.f - e) / (1.f + e);
}

// ---------------------------------------------------------------------------
// Persistent LSTM. Grid: 256 blocks x 512 threads (8 waves).
// mc = blk & 3 (batch group), jc = blk >> 2 (16-col j tile).
//
// ROUND-5 DESIGN RULE (from R1/R4 post-mortems): poll traffic must be TINY
// and data movement must be BATCHED and happen ONCE.
//  - R1: small flag poll but 16 SERIALIZED data RTs (~6us/step).
//  - R4: 1 batched data RT but the tag-poll storm (8KB/wave/iter x 2048
//    waves ~ 16TB/s at the LLC) congested every RT (~7us/step).
//  - R5: flags (32B/wave/iter poll) + ONE batched 4x dwordx4 data load.
//
// h stored PACKED bf16 (2/u32, no tags — flags gate validity).
// Per-wave flags: wave w consumes k in [w*128,(w+1)*128) = columns of
// producer blocks jc' in [w*8, w*8+8) -> polls only those 8 flags (one
// cache line) and proceeds independently (no block-wide max-of-64 wait).
//
// Publish ordering: h stores (sc0 sc1) -> S3 __syncthreads (per-thread
// vmcnt(0) = all stores acked at the coherence point) -> flag post.
// Consumers seeing flag >= t+1 therefore see h(t).
//
// WAR safety (buf parity, lag 2): block P overwrites buf[t&1] with h(t+2)
// only after all 8 of each of its waves' producer flags reached t+2; flag
// t+2 from block Q implies Q fully read h(t) (its part(t+1) store precedes
// its step-t+1 reduce/publish). All 64 group flags are covered by the
// union of P's 8 waves.
// ---------------------------------------------------------------------------
__global__ __launch_bounds__(NTHR, 1) void lstm_persist(
        const float* __restrict__ x, const float* __restrict__ Wx,
        const float* __restrict__ Wh, const float* __restrict__ bias,
        float* __restrict__ out, unsigned* __restrict__ hp0,
        unsigned* __restrict__ hp1, unsigned* __restrict__ flags)
{
    __shared__ float part[8][16][68];   // per-wave partial gate tiles
    __shared__ float gtile[16][68];     // reduced gates
    __shared__ float sbias[64];

    const int tid  = threadIdx.x;
    const int w    = tid >> 6;
    const int lane = tid & 63;
    const int blk  = blockIdx.x;
    const int mc   = blk & 3;     // batch-row group
    const int jc   = blk >> 2;    // 0..63  j group (16 j's)
    const int quad = lane >> 4;   // 0..3
    const int n    = lane & 15;   // MFMA row/col within tile
    const int gN   = n >> 2;      // gate index for B cols
    const int jl4  = n & 3;

    if (tid < 64) {
        int u = tid >> 4, nn = tid & 15;
        sbias[u * 16 + nn] = bias[(nn >> 2) * Hq + jc * 16 + u * 4 + (nn & 3)];
    }

    // ---- one-time: B fragments (bf16) into registers ----------------------
    // chunk s<4: Wh rows [w*128 + s*32, +32);  s>=4: Wx rows [w*128 + (s-4)*32, +32)
    short8 bs[4][8];
#pragma unroll
    for (int u = 0; u < 4; ++u) {
        const int col = gN * Hq + jc * 16 + u * 4 + jl4;
#pragma unroll
        for (int s = 0; s < 8; ++s) {
            const int kb = w * 128 + (s & 3) * 32 + quad * 8;
            const float* Wsrc = (s < 4) ? Wh : Wx;
#pragma unroll
            for (int j = 0; j < 8; ++j)
                bs[u][s][j] = f2bf(Wsrc[(size_t)(kb + j) * G4 + col]);
        }
    }

    float cstate = 0.f;          // cell state (threads 0..255)
    const int urow = tid >> 4;   // valid when tid<256
    const int ujl  = tid & 15;

    const int m_g = mc * 16 + n;                          // A row (batch)
    const float* xrow = x + (size_t)m_g * Tq * Hq + w * 128 + quad * 8;
    // packed-h: u32 word index; lane k-base = w*128 + quad*8 (even)
    const size_t hwoff = (size_t)m_g * (Hq / 2) + w * 64 + quad * 4;

    float4v acc0, acc1, acc2, acc3;

    auto mfma_chunk = [&](short8 a, int s) {
        acc0 = __builtin_amdgcn_mfma_f32_16x16x32_bf16(a, bs[0][s], acc0, 0, 0, 0);
        acc1 = __builtin_amdgcn_mfma_f32_16x16x32_bf16(a, bs[1][s], acc1, 0, 0, 0);
        acc2 = __builtin_amdgcn_mfma_f32_16x16x32_bf16(a, bs[2][s], acc2, 0, 0, 0);
        acc3 = __builtin_amdgcn_mfma_f32_16x16x32_bf16(a, bs[3][s], acc3, 0, 0, 0);
    };
    auto store_part = [&]() {
#pragma unroll
        for (int r = 0; r < 4; ++r) {
            part[w][quad * 4 + r][ 0 + n] = acc0[r];
            part[w][quad * 4 + r][16 + n] = acc1[r];
            part[w][quad * 4 + r][32 + n] = acc2[r];
            part[w][quad * 4 + r][48 + n] = acc3[r];
        }
    };
    auto xmfma = [&](const float4* xv) {
#pragma unroll
        for (int cs = 0; cs < 4; ++cs) {
            float4 v0 = xv[2 * cs], v1 = xv[2 * cs + 1];
            short8 a;
            a[0] = f2bf(v0.x); a[1] = f2bf(v0.y); a[2] = f2bf(v0.z); a[3] = f2bf(v0.w);
            a[4] = f2bf(v1.x); a[5] = f2bf(v1.y); a[6] = f2bf(v1.z); a[7] = f2bf(v1.w);
            mfma_chunk(a, 4 + cs);
        }
    };

    // wave w waits for its 8 producer blocks (columns k in [w*128,+128))
    auto poll_flags = [&](unsigned tgt) {
        const unsigned* fb = flags + mc * 64 + w * 8;
        for (;;) {
            unsigned f = aload_u(fb + (lane & 7));
            if (__all((int)(f >= tgt))) break;
        }
    };

    // ONE batched coherent load of this lane's packed h(t) slice (64 B),
    // then 16 MFMAs. Validity guaranteed by the flag poll.
    auto hload = [&](int t) {
        const unsigned* hb = (t & 1) ? hp1 : hp0;
        const unsigned* base = hb + hwoff;
        uint4v q0, q1, q2, q3;
        asm volatile(
            "global_load_dwordx4 %[a0], %[ad], off sc0 sc1\n\t"
            "global_load_dwordx4 %[a1], %[ad], off offset:64 sc0 sc1\n\t"
            "global_load_dwordx4 %[a2], %[ad], off offset:128 sc0 sc1\n\t"
            "global_load_dwordx4 %[a3], %[ad], off offset:192 sc0 sc1\n\t"
            "s_waitcnt vmcnt(0)"
            : [a0]"=v"(q0), [a1]"=v"(q1), [a2]"=v"(q2), [a3]"=v"(q3)
            : [ad]"v"(base)
            : "memory");
        auto mk = [&](uint4v q) {
            short8 a;
#pragma unroll
            for (int m = 0; m < 4; ++m) {
                a[2 * m]     = (short)(q[m] & 0xffffu);   // even k
                a[2 * m + 1] = (short)(q[m] >> 16);       // odd k
            }
            return a;
        };
        mfma_chunk(mk(q0), 0);
        mfma_chunk(mk(q1), 1);
        mfma_chunk(mk(q2), 2);
        mfma_chunk(mk(q3), 3);
    };

    // ---- prologue: part for t=0 (x contribution only; h == 0) -------------
    {
        float4 xv[8];
#pragma unroll
        for (int cs = 0; cs < 4; ++cs) {
            const float4* q = (const float4*)(xrow + cs * 32);
            xv[2 * cs] = q[0]; xv[2 * cs + 1] = q[1];
        }
        acc0 = acc1 = acc2 = acc3 = (float4v){0, 0, 0, 0};
        xmfma(xv);
        store_part();
    }

    for (int t = 0; t < Tq; ++t) {
        __syncthreads();   // S1: part(t) complete

        const bool notlast = (t + 1 < Tq);

        // issue x loads for t+1 EARLY: they must be acked by S3's vmcnt(0),
        // so give them the reduce+activation phase to complete
        float4 xv[8];
        if (notlast) {
            const float* ap = xrow + (size_t)(t + 1) * Hq;
#pragma unroll
            for (int cs = 0; cs < 4; ++cs) {
                const float4* q = (const float4*)(ap + cs * 32);
                xv[2 * cs] = q[0]; xv[2 * cs + 1] = q[1];
            }
        }

        // reduce 8 partials -> gates (1024 values, 2 per thread)
#pragma unroll
        for (int e = 0; e < 2; ++e) {
            int idx = tid + e * NTHR;
            int rr = idx >> 6, cc = idx & 63;
            float s = part[0][rr][cc];
#pragma unroll
            for (int ww = 1; ww < 8; ++ww) s += part[ww][rr][cc];
            gtile[rr][cc] = s + sbias[cc];
        }
        __syncthreads();   // S2: gtile ready; part free

        float hn = 0.f;
        int bg = 0, jg = 0;
        if (tid < 256) {
            const int u = ujl >> 2, j4 = ujl & 3;
            float gi = gtile[urow][u * 16 +  0 + j4];
            float gf = gtile[urow][u * 16 +  4 + j4];
            float gg = gtile[urow][u * 16 +  8 + j4];
            float go = gtile[urow][u * 16 + 12 + j4];
            float i_ = fsig(gi);
            float f_ = fsig(gf);
            float g_ = ftanh(gg);
            float o_ = fsig(go);
            cstate = f_ * cstate + i_ * g_;
            hn = o_ * ftanh(cstate);
            bg = mc * 16 + urow;
            jg = jc * 16 + ujl;
            if (notlast) {
                // pack 2 adjacent j's bf16 into one u32 cache-bypass store
                unsigned hp = (unsigned)(unsigned short)f2bf(hn);
                unsigned up = __shfl_down(hp, 1);
                if (!(tid & 1)) {
                    unsigned* hw = (t & 1) ? hp1 : hp0;
                    astore_u(hw + (size_t)bg * (Hq / 2) + (jg >> 1),
                             hp | (up << 16));
                }
            }
        }
        __syncthreads();   // S3: vmcnt(0) per thread -> all h stores acked

        if (notlast && tid == 0) astore_u(&flags[mc * 64 + jc], (unsigned)(t + 1));
        // forbid sinking the flag post below the poll (self-poll deadlock)
        asm volatile("" ::: "memory");

        // out store is off the critical path — after the flag post
        if (tid < 256) out[((size_t)bg * Tq + t) * Hq + jg] = hn;

        if (notlast) {
            acc0 = acc1 = acc2 = acc3 = (float4v){0, 0, 0, 0};
            xmfma(xv);         // overlaps flag propagation across the group
            poll_flags((unsigned)(t + 1));   // 32 B/iter: my 8 producers only
            hload(t);          // one batched RT + 16 MFMAs
            store_part();      // part for t+1
        }
    }
}

extern "C" void kernel_launch(void* const* d_in, const int* in_sizes, int n_in,
                              void* d_out, int out_size, void* d_ws, size_t ws_size,
                              hipStream_t stream) {
    const float* x    = (const float*)d_in[0];
    const float* Wx   = (const float*)d_in[1];
    const float* Wh   = (const float*)d_in[2];
    const float* bias = (const float*)d_in[3];
    float* out = (float*)d_out;

    // ws layout: flags[256] u32 (1 KB) | hp0[64*512] u32 (128 KB) | hp1 (128 KB)
    unsigned* flags = (unsigned*)d_ws;
    unsigned* hp0 = (unsigned*)((char*)d_ws + 1024);
    unsigned* hp1 = hp0 + Bq * (Hq / 2);

    // zero flags only (h reads are flag-gated; t=0 skips h entirely)
    hipMemsetAsync(d_ws, 0, 1024, stream);

    void* args[] = {(void*)&x, (void*)&Wx, (void*)&Wh, (void*)&bias,
                    (void*)&out, (void*)&hp0, (void*)&hp1, (void*)&flags};
    hipLaunchCooperativeKernel((const void*)lstm_persist, dim3(NBLK), dim3(NTHR),
                               args, 0, stream);
}